// Round 7
// baseline (950.163 us; speedup 1.0000x reference)
//
#include <hip/hip_runtime.h>

#define TLEN  512
#define HID   128
#define RSLOT 8    // ring slots per slice (power of 2) — sized to keep
                   // live ring set L2-resident: 8*4KB*2rings*24slices/XCD ~1.5MB

typedef __attribute__((ext_vector_type(8))) short          bf16x8;
typedef __attribute__((ext_vector_type(4))) float          f32x4;
typedef __attribute__((ext_vector_type(4))) unsigned short u16x4;
typedef unsigned long long u64;

#define LOG2E  1.4426950408889634f
#define LOG2E2 2.8853900817779268f

// RNE (cold paths: weights, x staging)
__device__ __forceinline__ unsigned short f2bf(float f) {
    union { float f; unsigned u; } v; v.f = f;
    unsigned r = v.u + 0x7fffu + ((v.u >> 16) & 1u);
    return (unsigned short)(r >> 16);
}
// round-half-up (hot path: h) — 2 ops instead of 5
__device__ __forceinline__ unsigned short f2bf_fast(float f) {
    union { float f; unsigned u; } v; v.f = f;
    return (unsigned short)((v.u + 0x8000u) >> 16);
}

// xs pre-scaled by log2(e): sigmoid(x_true)
__device__ __forceinline__ float sig_ps(float xs) {
    return __builtin_amdgcn_rcpf(1.0f + __builtin_exp2f(-xs));
}
// xs pre-scaled by 2*log2(e): tanh(x_true) = 2*sigmoid(2x)-1
__device__ __forceinline__ float tanh_ps(float xs) {
    return 2.0f * __builtin_amdgcn_rcpf(1.0f + __builtin_exp2f(-xs)) - 1.0f;
}

__device__ __forceinline__ int flag_peek(const int* f) {
    return __hip_atomic_load(f, __ATOMIC_RELAXED, __HIP_MEMORY_SCOPE_AGENT);
}
__device__ __forceinline__ int flag_spin(const int* f, int v) {
    int x = flag_peek(f);
    while (x < v) { __builtin_amdgcn_s_sleep(1); x = flag_peek(f); }
    return x;
}

// One LSTM layer over T steps for a 16-row batch slice. Uniform 8-wave block
// (register budget forbids wave specialization — R5 lesson). Flags pipelined:
// `pend`/`cpend` hold last step's fire-and-forget flag read; spin only when
// genuinely behind (warmup).
template<int MODE, bool CONS, bool PROD, bool WFC>
__device__ __forceinline__ void run_layer_p(
    const float* __restrict__ xin,
    const u64* __restrict__ rin, u64* __restrict__ rout,
    const int* pin_flag, int* cout_flag, const int* cin_flag, int* pout_flag,
    const float* __restrict__ wih, const float* __restrict__ whh,
    const float* __restrict__ bih, const float* __restrict__ bhh,
    unsigned short (* __restrict__ Abuf)[8 * 512],
    float* __restrict__ fcred,
    const int tid, const int wave, const int lane,
    const int n16, const int quad, const int bbase)
{
    constexpr int NKT  = MODE ? 8 : 5;      // K-tiles of 32
    constexpr int KX   = MODE ? 128 : 32;   // padded x-region width
    constexpr int DINL = MODE ? 128 : 6;    // real input features
    constexpr int HB0  = MODE ? 2048 : 512; // h-region start elem

    // ---- weights -> register/AGPR B fragments (prescaled) ----
    bf16x8 Wf[4][NKT];
    float  bb[4];
#pragma unroll
    for (int g = 0; g < 4; ++g) {
        const float sc = (g == 2) ? LOG2E2 : LOG2E;
        const int row = g * 128 + wave * 16 + n16;
        bb[g] = (bih[row] + bhh[row]) * sc;
#pragma unroll
        for (int kt = 0; kt < NKT; ++kt) {
            const int kbase = kt * 32 + quad * 8;
            bf16x8 wv;
#pragma unroll
            for (int j = 0; j < 8; ++j) {
                const int k = kbase + j;
                float f;
                if (k < KX) f = (k < DINL) ? wih[row * DINL + k] : 0.0f;
                else        f = whh[row * HID + (k - KX)];
                wv[j] = (short)f2bf(f * sc);
            }
            Wf[g][kt] = wv;
        }
    }

    // ---- prologue: zero h-region; stage entry 0 -> LDS, 1..3 -> queue ----
    { u16x4 z = {0, 0, 0, 0}; *(u16x4*)&Abuf[0][HB0 + tid * 4] = z; }
    u64 q0 = 0, q1 = 0, q2 = 0, q3 = 0;
    float pfx0 = 0.0f;
    int pend = 0, cpend = 0;
    if constexpr (CONS) {
        flag_spin(pin_flag, 1);
        u64 v0 = __hip_atomic_load(rin + tid, __ATOMIC_RELAXED, __HIP_MEMORY_SCOPE_AGENT);
        *(u64*)&Abuf[0][tid * 4] = v0;
        pend = flag_spin(pin_flag, 4);
        q0 = __hip_atomic_load(rin + 1 * 512 + tid, __ATOMIC_RELAXED, __HIP_MEMORY_SCOPE_AGENT);
        q1 = __hip_atomic_load(rin + 2 * 512 + tid, __ATOMIC_RELAXED, __HIP_MEMORY_SCOPE_AGENT);
        q2 = __hip_atomic_load(rin + 3 * 512 + tid, __ATOMIC_RELAXED, __HIP_MEMORY_SCOPE_AGENT);
    } else {
        const int m = tid >> 5, k = tid & 31;
        float v = (k < DINL) ? xin[((bbase + m) * TLEN + 0) * DINL + k] : 0.0f;
        Abuf[0][((k >> 3) * 16 + m) * 8 + (k & 7)] = f2bf(v);
        if (k < DINL) pfx0 = xin[((bbase + m) * TLEN + 1) * DINL + k];
    }
    if constexpr (PROD) cpend = -(1 << 30);   // force first real check to spin

    float cst[4] = {0.f, 0.f, 0.f, 0.f};

    for (int t = 0; t < TLEN; ++t) {
        const int cur = t & 1, nxt = cur ^ 1;
        __syncthreads();   // Abuf[cur] ready; all vmem drained (vmcnt(0))

        // ---- publish progress (fire-and-forget) ----
        if (tid == 0) {
            if constexpr (CONS)   // entries <= t+3 landed (drained by barrier)
                __hip_atomic_store(cout_flag, t + 4, __ATOMIC_RELAXED, __HIP_MEMORY_SCOPE_AGENT);
            if constexpr (PROD)   // entries <= t-2 globally visible
                if (t >= 2)
                    __hip_atomic_store(pout_flag, t - 1, __ATOMIC_RELAXED, __HIP_MEMORY_SCOPE_AGENT);
        }

        // ---- ring load of entry t+4 (issued early; gated by LAST step's flag) ----
        if constexpr (CONS) {
            if (t + 4 < TLEN) {
                if (pend < t + 5) pend = flag_spin(pin_flag, t + 5);  // rare
                q3 = __hip_atomic_load(rin + ((t + 4) & (RSLOT - 1)) * 512 + tid,
                                       __ATOMIC_RELAXED, __HIP_MEMORY_SCOPE_AGENT);
                pend = flag_peek(pin_flag);   // deferred refresh, used next step
            }
        }

        // ---- producer: store entry t-1 (h(t-1) in Abuf[cur]) ----
        if constexpr (PROD) {
            if (t >= 1) {
                const int e = t - 1;
                if ((e & 3) == 0 && e + 4 > RSLOT && cpend < e + 4 - RSLOT)
                    cpend = flag_spin(cin_flag, e + 4 - RSLOT);       // rare
                u64 hv = *(const u64*)&Abuf[cur][HB0 + tid * 4];
                __hip_atomic_store(rout + (e & (RSLOT - 1)) * 512 + tid, hv,
                                   __ATOMIC_RELAXED, __HIP_MEMORY_SCOPE_AGENT);
                if ((e & 3) == 1) cpend = flag_peek(cin_flag);        // deferred refresh
            }
        }

        // ---- prefetch x(t+2) (MODE 0) ----
        float pfx1 = 0.0f;
        if constexpr (!CONS) {
            if (t + 2 < TLEN) {
                const int m = tid >> 5, k = tid & 31;
                if (k < DINL) pfx1 = xin[((bbase + m) * TLEN + (t + 2)) * DINL + k];
            }
        }

        // ---- gates = A @ W^T (fp32 accum, bias pre-loaded into acc) ----
        f32x4 acc[4];
#pragma unroll
        for (int g = 0; g < 4; ++g) {
            f32x4 bi = {bb[g], bb[g], bb[g], bb[g]};
            acc[g] = bi;
        }
#pragma unroll
        for (int kt = 0; kt < NKT; ++kt) {
            bf16x8 a = *(const bf16x8*)&Abuf[cur][kt * 512 + lane * 8];
#pragma unroll
            for (int g = 0; g < 4; ++g)
                acc[g] = __builtin_amdgcn_mfma_f32_16x16x32_bf16(a, Wf[g][kt], acc[g], 0, 0, 0);
        }

        // ---- in-lane LSTM cell update ----
        unsigned short hb[4]; float hf[4];
#pragma unroll
        for (int r = 0; r < 4; ++r) {
            const float iv = sig_ps (acc[0][r]);
            const float fv = sig_ps (acc[1][r]);
            const float gv = tanh_ps(acc[2][r]);
            const float ov = sig_ps (acc[3][r]);
            const float c  = fv * cst[r] + iv * gv;
            cst[r] = c;
            const float h  = ov * tanh_ps(c * LOG2E2);
            hf[r] = h;
            hb[r] = f2bf_fast(h);
        }

        // ---- h -> Abuf[nxt] h-region (A-layout, own recurrence) ----
        {
            const int j  = wave * 16 + n16;
            const int kh = KX + j;
            const int kt = kh >> 5, kk = kh & 31;
            const int eb = kt * 512 + (kk >> 3) * 128 + (kk & 7);
#pragma unroll
            for (int r = 0; r < 4; ++r)
                Abuf[nxt][eb + (quad * 4 + r) * 8] = hb[r];
        }
        if constexpr (WFC) {
            if (t == TLEN - 1)
#pragma unroll
                for (int r = 0; r < 4; ++r)
                    fcred[(quad * 4 + r) * HID + wave * 16 + n16] = hf[r];
        }

        // ---- commit next-step x into Abuf[nxt] x-region; shift queue ----
        if (t + 1 < TLEN) {
            if constexpr (CONS) {
                *(u64*)&Abuf[nxt][tid * 4] = q0;   // entry t+1 (loaded 3 steps ago)
                q0 = q1; q1 = q2; q2 = q3;
            } else {
                const int m = tid >> 5, k = tid & 31;
                Abuf[nxt][((k >> 3) * 16 + m) * 8 + (k & 7)] = f2bf(pfx0);
                pfx0 = pfx1;
            }
        }
    }

    // ---- producer epilogue: flush entry T-1, final flags ----
    if constexpr (PROD) {
        __syncthreads();   // h(T-1) in Abuf[TLEN&1]; step T-1 stores drained
        if (tid == 0)
            __hip_atomic_store(pout_flag, TLEN - 1, __ATOMIC_RELAXED, __HIP_MEMORY_SCOPE_AGENT);
        {
            flag_spin(cin_flag, TLEN - RSLOT);
            u64 hv = *(const u64*)&Abuf[TLEN & 1][HB0 + tid * 4];
            __hip_atomic_store(rout + ((TLEN - 1) & (RSLOT - 1)) * 512 + tid, hv,
                               __ATOMIC_RELAXED, __HIP_MEMORY_SCOPE_AGENT);
        }
        __syncthreads();   // drain entry T-1 stores
        if (tid == 0)
            __hip_atomic_store(pout_flag, TLEN, __ATOMIC_RELAXED, __HIP_MEMORY_SCOPE_AGENT);
    }
}

extern "C" __global__ __launch_bounds__(512, 2)
void lstm3_pipe_kernel(const float* __restrict__ xin,
    const float* __restrict__ wih0, const float* __restrict__ whh0,
    const float* __restrict__ bih0, const float* __restrict__ bhh0,
    const float* __restrict__ wih1, const float* __restrict__ whh1,
    const float* __restrict__ bih1, const float* __restrict__ bhh1,
    const float* __restrict__ wih2, const float* __restrict__ whh2,
    const float* __restrict__ bih2, const float* __restrict__ bhh2,
    const float* __restrict__ fcw, const float* __restrict__ fcb,
    float* __restrict__ out,
    int* __restrict__ flags, u64* __restrict__ ring0, u64* __restrict__ ring1)
{
    __shared__ unsigned short Abuf[2][8 * 512];   // 16 KB
    __shared__ float fcred[16 * HID];             // 8 KB

    const int tid   = threadIdx.x;
    const int wave  = tid >> 6;
    const int lane  = tid & 63;
    const int n16   = lane & 15;
    const int quad  = lane >> 4;
    const int layer = blockIdx.x >> 6;
    const int slice = blockIdx.x & 63;
    const int bbase = slice * 16;

    u64* r0 = ring0 + (size_t)slice * (RSLOT * 512);
    u64* r1 = ring1 + (size_t)slice * (RSLOT * 512);
    // each flag on its own 256 B line
    int* prod0 = flags + (size_t)(0 * 64 + slice) * 64;
    int* prod1 = flags + (size_t)(1 * 64 + slice) * 64;
    int* cons1 = flags + (size_t)(2 * 64 + slice) * 64;
    int* cons2 = flags + (size_t)(3 * 64 + slice) * 64;

    if (layer == 0) {
        run_layer_p<0, false, true, false>(xin, nullptr, r0,
            nullptr, nullptr, cons1, prod0,
            wih0, whh0, bih0, bhh0, Abuf, fcred, tid, wave, lane, n16, quad, bbase);
    } else if (layer == 1) {
        run_layer_p<1, true, true, false>(nullptr, r0, r1,
            prod0, cons1, cons2, prod1,
            wih1, whh1, bih1, bhh1, Abuf, fcred, tid, wave, lane, n16, quad, bbase);
    } else {
        run_layer_p<1, true, false, true>(nullptr, r1, nullptr,
            prod1, cons2, nullptr, nullptr,
            wih2, whh2, bih2, bhh2, Abuf, fcred, tid, wave, lane, n16, quad, bbase);
        __syncthreads();
        if (tid < 16) {
            float s = 0.0f;
#pragma unroll 8
            for (int j = 0; j < HID; ++j) s += fcw[j] * fcred[tid * HID + j];
            out[bbase + tid] = s + fcb[0];
        }
    }
}

extern "C" void kernel_launch(void* const* d_in, const int* in_sizes, int n_in,
                              void* d_out, int out_size, void* d_ws, size_t ws_size,
                              hipStream_t stream) {
    (void)in_sizes; (void)n_in; (void)out_size; (void)ws_size;
    const float* x    = (const float*)d_in[0];
    const float* wih0 = (const float*)d_in[1];
    const float* whh0 = (const float*)d_in[2];
    const float* bih0 = (const float*)d_in[3];
    const float* bhh0 = (const float*)d_in[4];
    const float* wih1 = (const float*)d_in[5];
    const float* whh1 = (const float*)d_in[6];
    const float* bih1 = (const float*)d_in[7];
    const float* bhh1 = (const float*)d_in[8];
    const float* wih2 = (const float*)d_in[9];
    const float* whh2 = (const float*)d_in[10];
    const float* bih2 = (const float*)d_in[11];
    const float* bhh2 = (const float*)d_in[12];
    const float* fcw  = (const float*)d_in[13];
    const float* fcb  = (const float*)d_in[14];
    float* out = (float*)d_out;

    // ws: flags 64 KB (poison-negative = not ready), ring0 2 MB, ring1 2 MB
    int* flags = (int*)d_ws;
    u64* ring0 = (u64*)((char*)d_ws + 65536);
    u64* ring1 = ring0 + (size_t)64 * RSLOT * 512;

    lstm3_pipe_kernel<<<dim3(192), dim3(512), 0, stream>>>(
        x, wih0, whh0, bih0, bhh0, wih1, whh1, bih1, bhh1,
        wih2, whh2, bih2, bhh2, fcw, fcb, out, flags, ring0, ring1);
}

// Round 8
// 938.734 us; speedup vs baseline: 1.0122x; 1.0122x over previous
//
#include <hip/hip_runtime.h>

#define TLEN  512
#define HID   128
#define RSLOT 32   // ring slots per slice — band width, NOT residency (R7 lesson)
#define QD    8    // consumer prefetch distance (register queue depth)

typedef __attribute__((ext_vector_type(8))) short          bf16x8;
typedef __attribute__((ext_vector_type(4))) float          f32x4;
typedef __attribute__((ext_vector_type(4))) unsigned short u16x4;
typedef unsigned long long u64;

#define LOG2E  1.4426950408889634f
#define LOG2E2 2.8853900817779268f

// RNE (cold paths: weights, x staging)
__device__ __forceinline__ unsigned short f2bf(float f) {
    union { float f; unsigned u; } v; v.f = f;
    unsigned r = v.u + 0x7fffu + ((v.u >> 16) & 1u);
    return (unsigned short)(r >> 16);
}
// round-half-up (hot path: h)
__device__ __forceinline__ unsigned short f2bf_fast(float f) {
    union { float f; unsigned u; } v; v.f = f;
    return (unsigned short)((v.u + 0x8000u) >> 16);
}

__device__ __forceinline__ float sig_ps(float xs) {
    return __builtin_amdgcn_rcpf(1.0f + __builtin_exp2f(-xs));
}
__device__ __forceinline__ float tanh_ps(float xs) {
    return 2.0f * __builtin_amdgcn_rcpf(1.0f + __builtin_exp2f(-xs)) - 1.0f;
}

__device__ __forceinline__ int flag_peek(const int* f) {
    return __hip_atomic_load(f, __ATOMIC_RELAXED, __HIP_MEMORY_SCOPE_AGENT);
}
__device__ __forceinline__ int flag_spin(const int* f, int v) {
    int x = flag_peek(f);
    while (x < v) { __builtin_amdgcn_s_sleep(1); x = flag_peek(f); }
    return x;
}

// One LSTM layer over T steps for a 16-row batch slice. Uniform 8-wave block.
// Consumer: depth-8 register queue. At step t: q[0..6] hold entries t+1..t+7;
// load entry t+8 (gated by LAST step's flag value) into qn; commit q[0] to
// Abuf[nxt]; shift. Producer ~10 steps ahead; backpressure cap ~34 -> ~24
// steps of elastic slack between pipeline stages.
template<int MODE, bool CONS, bool PROD, bool WFC>
__device__ __forceinline__ void run_layer_p(
    const float* __restrict__ xin,
    const u64* __restrict__ rin, u64* __restrict__ rout,
    const int* pin_flag, int* cout_flag, const int* cin_flag, int* pout_flag,
    const float* __restrict__ wih, const float* __restrict__ whh,
    const float* __restrict__ bih, const float* __restrict__ bhh,
    unsigned short (* __restrict__ Abuf)[8 * 512],
    float* __restrict__ fcred,
    const int tid, const int wave, const int lane,
    const int n16, const int quad, const int bbase)
{
    constexpr int NKT  = MODE ? 8 : 5;      // K-tiles of 32
    constexpr int KX   = MODE ? 128 : 32;   // padded x-region width
    constexpr int DINL = MODE ? 128 : 6;    // real input features
    constexpr int HB0  = MODE ? 2048 : 512; // h-region start elem

    // ---- weights -> register/AGPR B fragments (prescaled) ----
    bf16x8 Wf[4][NKT];
    float  bb[4];
#pragma unroll
    for (int g = 0; g < 4; ++g) {
        const float sc = (g == 2) ? LOG2E2 : LOG2E;
        const int row = g * 128 + wave * 16 + n16;
        bb[g] = (bih[row] + bhh[row]) * sc;
#pragma unroll
        for (int kt = 0; kt < NKT; ++kt) {
            const int kbase = kt * 32 + quad * 8;
            bf16x8 wv;
#pragma unroll
            for (int j = 0; j < 8; ++j) {
                const int k = kbase + j;
                float f;
                if (k < KX) f = (k < DINL) ? wih[row * DINL + k] : 0.0f;
                else        f = whh[row * HID + (k - KX)];
                wv[j] = (short)f2bf(f * sc);
            }
            Wf[g][kt] = wv;
        }
    }

    // ---- prologue: zero h-region; entry 0 -> LDS, entries 1..QD-1 -> queue ----
    { u16x4 z = {0, 0, 0, 0}; *(u16x4*)&Abuf[0][HB0 + tid * 4] = z; }
    u64 q[QD - 1]; u64 qn = 0;
#pragma unroll
    for (int i = 0; i < QD - 1; ++i) q[i] = 0;
    float pfx0 = 0.0f;
    int pend = 0, cpend = 0;
    if constexpr (CONS) {
        flag_spin(pin_flag, 1);
        u64 v0 = __hip_atomic_load(rin + tid, __ATOMIC_RELAXED, __HIP_MEMORY_SCOPE_AGENT);
        *(u64*)&Abuf[0][tid * 4] = v0;
        pend = flag_spin(pin_flag, QD);
#pragma unroll
        for (int i = 0; i < QD - 1; ++i)
            q[i] = __hip_atomic_load(rin + (i + 1) * 512 + tid, __ATOMIC_RELAXED, __HIP_MEMORY_SCOPE_AGENT);
    } else {
        const int m = tid >> 5, k = tid & 31;
        float v = (k < DINL) ? xin[((bbase + m) * TLEN + 0) * DINL + k] : 0.0f;
        Abuf[0][((k >> 3) * 16 + m) * 8 + (k & 7)] = f2bf(v);
        if (k < DINL) pfx0 = xin[((bbase + m) * TLEN + 1) * DINL + k];
    }
    if constexpr (PROD) cpend = -(1 << 30);   // force first real check to spin

    float cst[4] = {0.f, 0.f, 0.f, 0.f};

    for (int t = 0; t < TLEN; ++t) {
        const int cur = t & 1, nxt = cur ^ 1;
        __syncthreads();   // Abuf[cur] ready; all vmem drained (vmcnt(0))

        // ---- ring load of entry t+QD (longest pole — issue first) ----
        if constexpr (CONS) {
            if (t + QD < TLEN) {
                if (pend < t + QD + 1) pend = flag_spin(pin_flag, t + QD + 1);  // rare
                qn = __hip_atomic_load(rin + ((t + QD) & (RSLOT - 1)) * 512 + tid,
                                       __ATOMIC_RELAXED, __HIP_MEMORY_SCOPE_AGENT);
                pend = flag_peek(pin_flag);   // deferred refresh, used next step
            }
        }

        // ---- publish progress (fire-and-forget) ----
        if (tid == 0) {
            if constexpr (CONS)   // entries <= t+QD-1 landed (drained by barrier)
                __hip_atomic_store(cout_flag, t + QD, __ATOMIC_RELAXED, __HIP_MEMORY_SCOPE_AGENT);
            if constexpr (PROD)   // entries <= t-2 globally visible
                if (t >= 2)
                    __hip_atomic_store(pout_flag, t - 1, __ATOMIC_RELAXED, __HIP_MEMORY_SCOPE_AGENT);
        }

        // ---- producer: store entry t-1 (h(t-1) in Abuf[cur]) ----
        if constexpr (PROD) {
            if (t >= 1) {
                const int e = t - 1;
                if ((e & 3) == 0 && e + 4 > RSLOT && cpend < e + 4 - RSLOT)
                    cpend = flag_spin(cin_flag, e + 4 - RSLOT);       // rare
                u64 hv = *(const u64*)&Abuf[cur][HB0 + tid * 4];
                __hip_atomic_store(rout + (e & (RSLOT - 1)) * 512 + tid, hv,
                                   __ATOMIC_RELAXED, __HIP_MEMORY_SCOPE_AGENT);
                if ((e & 3) == 1) cpend = flag_peek(cin_flag);        // deferred refresh
            }
        }

        // ---- prefetch x(t+2) (MODE 0) ----
        float pfx1 = 0.0f;
        if constexpr (!CONS) {
            if (t + 2 < TLEN) {
                const int m = tid >> 5, k = tid & 31;
                if (k < DINL) pfx1 = xin[((bbase + m) * TLEN + (t + 2)) * DINL + k];
            }
        }

        // ---- gates = A @ W^T (fp32 accum, bias pre-loaded into acc) ----
        f32x4 acc[4];
#pragma unroll
        for (int g = 0; g < 4; ++g) {
            f32x4 bi = {bb[g], bb[g], bb[g], bb[g]};
            acc[g] = bi;
        }
#pragma unroll
        for (int kt = 0; kt < NKT; ++kt) {
            bf16x8 a = *(const bf16x8*)&Abuf[cur][kt * 512 + lane * 8];
#pragma unroll
            for (int g = 0; g < 4; ++g)
                acc[g] = __builtin_amdgcn_mfma_f32_16x16x32_bf16(a, Wf[g][kt], acc[g], 0, 0, 0);
        }

        // ---- in-lane LSTM cell update ----
        unsigned short hb[4]; float hf[4];
#pragma unroll
        for (int r = 0; r < 4; ++r) {
            const float iv = sig_ps (acc[0][r]);
            const float fv = sig_ps (acc[1][r]);
            const float gv = tanh_ps(acc[2][r]);
            const float ov = sig_ps (acc[3][r]);
            const float c  = fv * cst[r] + iv * gv;
            cst[r] = c;
            const float h  = ov * tanh_ps(c * LOG2E2);
            hf[r] = h;
            hb[r] = f2bf_fast(h);
        }

        // ---- h -> Abuf[nxt] h-region (A-layout, own recurrence) ----
        {
            const int j  = wave * 16 + n16;
            const int kh = KX + j;
            const int kt = kh >> 5, kk = kh & 31;
            const int eb = kt * 512 + (kk >> 3) * 128 + (kk & 7);
#pragma unroll
            for (int r = 0; r < 4; ++r)
                Abuf[nxt][eb + (quad * 4 + r) * 8] = hb[r];
        }
        if constexpr (WFC) {
            if (t == TLEN - 1)
#pragma unroll
                for (int r = 0; r < 4; ++r)
                    fcred[(quad * 4 + r) * HID + wave * 16 + n16] = hf[r];
        }

        // ---- commit entry t+1 into Abuf[nxt] x-region; shift queue ----
        if (t + 1 < TLEN) {
            if constexpr (CONS) {
                *(u64*)&Abuf[nxt][tid * 4] = q[0];
#pragma unroll
                for (int i = 0; i < QD - 2; ++i) q[i] = q[i + 1];
                q[QD - 2] = qn;
            } else {
                const int m = tid >> 5, k = tid & 31;
                Abuf[nxt][((k >> 3) * 16 + m) * 8 + (k & 7)] = f2bf(pfx0);
                pfx0 = pfx1;
            }
        }
    }

    // ---- producer epilogue: flush entry T-1, final flags ----
    if constexpr (PROD) {
        __syncthreads();   // h(T-1) in Abuf[TLEN&1]; step T-1 stores drained
        if (tid == 0)
            __hip_atomic_store(pout_flag, TLEN - 1, __ATOMIC_RELAXED, __HIP_MEMORY_SCOPE_AGENT);
        {
            flag_spin(cin_flag, TLEN - RSLOT);
            u64 hv = *(const u64*)&Abuf[TLEN & 1][HB0 + tid * 4];
            __hip_atomic_store(rout + ((TLEN - 1) & (RSLOT - 1)) * 512 + tid, hv,
                               __ATOMIC_RELAXED, __HIP_MEMORY_SCOPE_AGENT);
        }
        __syncthreads();   // drain entry T-1 stores
        if (tid == 0)
            __hip_atomic_store(pout_flag, TLEN, __ATOMIC_RELAXED, __HIP_MEMORY_SCOPE_AGENT);
    }
}

extern "C" __global__ __launch_bounds__(512, 1)
void lstm3_pipe_kernel(const float* __restrict__ xin,
    const float* __restrict__ wih0, const float* __restrict__ whh0,
    const float* __restrict__ bih0, const float* __restrict__ bhh0,
    const float* __restrict__ wih1, const float* __restrict__ whh1,
    const float* __restrict__ bih1, const float* __restrict__ bhh1,
    const float* __restrict__ wih2, const float* __restrict__ whh2,
    const float* __restrict__ bih2, const float* __restrict__ bhh2,
    const float* __restrict__ fcw, const float* __restrict__ fcb,
    float* __restrict__ out,
    int* __restrict__ flags, u64* __restrict__ ring0, u64* __restrict__ ring1)
{
    __shared__ unsigned short Abuf[2][8 * 512];   // 16 KB
    __shared__ float fcred[16 * HID];             // 8 KB

    const int tid   = threadIdx.x;
    const int wave  = tid >> 6;
    const int lane  = tid & 63;
    const int n16   = lane & 15;
    const int quad  = lane >> 4;
    const int layer = blockIdx.x >> 6;
    const int slice = blockIdx.x & 63;
    const int bbase = slice * 16;

    u64* r0 = ring0 + (size_t)slice * (RSLOT * 512);
    u64* r1 = ring1 + (size_t)slice * (RSLOT * 512);
    // each flag on its own 256 B line
    int* prod0 = flags + (size_t)(0 * 64 + slice) * 64;
    int* prod1 = flags + (size_t)(1 * 64 + slice) * 64;
    int* cons1 = flags + (size_t)(2 * 64 + slice) * 64;
    int* cons2 = flags + (size_t)(3 * 64 + slice) * 64;

    if (layer == 0) {
        run_layer_p<0, false, true, false>(xin, nullptr, r0,
            nullptr, nullptr, cons1, prod0,
            wih0, whh0, bih0, bhh0, Abuf, fcred, tid, wave, lane, n16, quad, bbase);
    } else if (layer == 1) {
        run_layer_p<1, true, true, false>(nullptr, r0, r1,
            prod0, cons1, cons2, prod1,
            wih1, whh1, bih1, bhh1, Abuf, fcred, tid, wave, lane, n16, quad, bbase);
    } else {
        run_layer_p<1, true, false, true>(nullptr, r1, nullptr,
            prod1, cons2, nullptr, nullptr,
            wih2, whh2, bih2, bhh2, Abuf, fcred, tid, wave, lane, n16, quad, bbase);
        __syncthreads();
        if (tid < 16) {
            float s = 0.0f;
#pragma unroll 8
            for (int j = 0; j < HID; ++j) s += fcw[j] * fcred[tid * HID + j];
            out[bbase + tid] = s + fcb[0];
        }
    }
}

extern "C" void kernel_launch(void* const* d_in, const int* in_sizes, int n_in,
                              void* d_out, int out_size, void* d_ws, size_t ws_size,
                              hipStream_t stream) {
    (void)in_sizes; (void)n_in; (void)out_size; (void)ws_size;
    const float* x    = (const float*)d_in[0];
    const float* wih0 = (const float*)d_in[1];
    const float* whh0 = (const float*)d_in[2];
    const float* bih0 = (const float*)d_in[3];
    const float* bhh0 = (const float*)d_in[4];
    const float* wih1 = (const float*)d_in[5];
    const float* whh1 = (const float*)d_in[6];
    const float* bih1 = (const float*)d_in[7];
    const float* bhh1 = (const float*)d_in[8];
    const float* wih2 = (const float*)d_in[9];
    const float* whh2 = (const float*)d_in[10];
    const float* bih2 = (const float*)d_in[11];
    const float* bhh2 = (const float*)d_in[12];
    const float* fcw  = (const float*)d_in[13];
    const float* fcb  = (const float*)d_in[14];
    float* out = (float*)d_out;

    // ws: flags 64 KB (poison-negative = not ready), ring0 8 MB, ring1 8 MB
    int* flags = (int*)d_ws;
    u64* ring0 = (u64*)((char*)d_ws + 65536);
    u64* ring1 = ring0 + (size_t)64 * RSLOT * 512;

    lstm3_pipe_kernel<<<dim3(192), dim3(512), 0, stream>>>(
        x, wih0, whh0, bih0, bhh0, wih1, whh1, bih1, bhh1,
        wih2, whh2, bih2, bhh2, fcw, fcb, out, flags, ring0, ring1);
}

// Round 9
// 885.097 us; speedup vs baseline: 1.0735x; 1.0606x over previous
//
#include <hip/hip_runtime.h>

#define TLEN  512
#define HID   128
#define RSLOT 16   // ring slots/slice; per-XCD live set = 8 slices*2 rings*16*4KB = 1 MB (L2-resident)
#define QD    4    // consumer prefetch distance (R8: depth beyond 4 is irrelevant)

typedef __attribute__((ext_vector_type(8))) short          bf16x8;
typedef __attribute__((ext_vector_type(4))) float          f32x4;
typedef __attribute__((ext_vector_type(4))) unsigned short u16x4;
typedef unsigned long long u64;

#define LOG2E  1.4426950408889634f
#define LOG2E2 2.8853900817779268f

// RNE (cold paths: weights, x staging)
__device__ __forceinline__ unsigned short f2bf(float f) {
    union { float f; unsigned u; } v; v.f = f;
    unsigned r = v.u + 0x7fffu + ((v.u >> 16) & 1u);
    return (unsigned short)(r >> 16);
}
// round-half-up (hot path: h)
__device__ __forceinline__ unsigned short f2bf_fast(float f) {
    union { float f; unsigned u; } v; v.f = f;
    return (unsigned short)((v.u + 0x8000u) >> 16);
}

__device__ __forceinline__ float sig_ps(float xs) {
    return __builtin_amdgcn_rcpf(1.0f + __builtin_exp2f(-xs));
}
__device__ __forceinline__ float tanh_ps(float xs) {
    return 2.0f * __builtin_amdgcn_rcpf(1.0f + __builtin_exp2f(-xs)) - 1.0f;
}

__device__ __forceinline__ int flag_peek(const int* f) {
    return __hip_atomic_load(f, __ATOMIC_RELAXED, __HIP_MEMORY_SCOPE_AGENT);
}
__device__ __forceinline__ int flag_spin(const int* f, int v) {
    int x = flag_peek(f);
    while (x < v) { __builtin_amdgcn_s_sleep(1); x = flag_peek(f); }
    return x;
}

// Ring data: producer stores WORKGROUP scope (plain global_store -> dirty in
// the XCD's L2, NO write-through); consumer loads AGENT scope (sc0: L1-bypass,
// hits the SAME XCD's L2 because all 3 stages of a slice are placed on one XCD
// via bid = ((s>>3)*3 + layer)*8 + (s&7), using the measured bid&7 -> XCD
// round-robin). Flags stay agent/L3 (correct under any placement); producer's
// barrier (vmcnt 0) drains data to L2 before the next-step flag publish.
template<int MODE, bool CONS, bool PROD, bool WFC>
__device__ __forceinline__ void run_layer_p(
    const float* __restrict__ xin,
    const u64* __restrict__ rin, u64* __restrict__ rout,
    const int* pin_flag, int* cout_flag, const int* cin_flag, int* pout_flag,
    const float* __restrict__ wih, const float* __restrict__ whh,
    const float* __restrict__ bih, const float* __restrict__ bhh,
    unsigned short (* __restrict__ Abuf)[8 * 512],
    float* __restrict__ fcred,
    const int tid, const int wave, const int lane,
    const int n16, const int quad, const int bbase)
{
    constexpr int NKT  = MODE ? 8 : 5;      // K-tiles of 32
    constexpr int KX   = MODE ? 128 : 32;   // padded x-region width
    constexpr int DINL = MODE ? 128 : 6;    // real input features
    constexpr int HB0  = MODE ? 2048 : 512; // h-region start elem

    // ---- weights -> register/AGPR B fragments (prescaled) ----
    bf16x8 Wf[4][NKT];
    float  bb[4];
#pragma unroll
    for (int g = 0; g < 4; ++g) {
        const float sc = (g == 2) ? LOG2E2 : LOG2E;
        const int row = g * 128 + wave * 16 + n16;
        bb[g] = (bih[row] + bhh[row]) * sc;
#pragma unroll
        for (int kt = 0; kt < NKT; ++kt) {
            const int kbase = kt * 32 + quad * 8;
            bf16x8 wv;
#pragma unroll
            for (int j = 0; j < 8; ++j) {
                const int k = kbase + j;
                float f;
                if (k < KX) f = (k < DINL) ? wih[row * DINL + k] : 0.0f;
                else        f = whh[row * HID + (k - KX)];
                wv[j] = (short)f2bf(f * sc);
            }
            Wf[g][kt] = wv;
        }
    }

    // ---- prologue: zero h-region; entry 0 -> LDS, entries 1..QD-1 -> queue ----
    { u16x4 z = {0, 0, 0, 0}; *(u16x4*)&Abuf[0][HB0 + tid * 4] = z; }
    u64 q[QD - 1]; u64 qn = 0;
#pragma unroll
    for (int i = 0; i < QD - 1; ++i) q[i] = 0;
    float pfx0 = 0.0f;
    int pend = 0, cpend = 0;
    if constexpr (CONS) {
        flag_spin(pin_flag, 1);
        u64 v0 = __hip_atomic_load(rin + tid, __ATOMIC_RELAXED, __HIP_MEMORY_SCOPE_AGENT);
        *(u64*)&Abuf[0][tid * 4] = v0;
        pend = flag_spin(pin_flag, QD);
#pragma unroll
        for (int i = 0; i < QD - 1; ++i)
            q[i] = __hip_atomic_load(rin + (i + 1) * 512 + tid, __ATOMIC_RELAXED, __HIP_MEMORY_SCOPE_AGENT);
    } else {
        const int m = tid >> 5, k = tid & 31;
        float v = (k < DINL) ? xin[((bbase + m) * TLEN + 0) * DINL + k] : 0.0f;
        Abuf[0][((k >> 3) * 16 + m) * 8 + (k & 7)] = f2bf(v);
        if (k < DINL) pfx0 = xin[((bbase + m) * TLEN + 1) * DINL + k];
    }
    if constexpr (PROD) cpend = -(1 << 30);   // force first real check to spin

    float cst[4] = {0.f, 0.f, 0.f, 0.f};

    for (int t = 0; t < TLEN; ++t) {
        const int cur = t & 1, nxt = cur ^ 1;
        __syncthreads();   // Abuf[cur] ready; all vmem drained (vmcnt(0))

        // ---- ring load of entry t+QD (longest pole — issue first) ----
        if constexpr (CONS) {
            if (t + QD < TLEN) {
                if (pend < t + QD + 1) pend = flag_spin(pin_flag, t + QD + 1);  // rare
                qn = __hip_atomic_load(rin + ((t + QD) & (RSLOT - 1)) * 512 + tid,
                                       __ATOMIC_RELAXED, __HIP_MEMORY_SCOPE_AGENT);
                pend = flag_peek(pin_flag);   // deferred refresh, used next step
            }
        }

        // ---- publish progress (fire-and-forget) ----
        if (tid == 0) {
            if constexpr (CONS)   // entries <= t+QD-1 landed (drained by barrier)
                __hip_atomic_store(cout_flag, t + QD, __ATOMIC_RELAXED, __HIP_MEMORY_SCOPE_AGENT);
            if constexpr (PROD)   // entries <= t-2 in L2 (drained at my barrier)
                if (t >= 2)
                    __hip_atomic_store(pout_flag, t - 1, __ATOMIC_RELAXED, __HIP_MEMORY_SCOPE_AGENT);
        }

        // ---- producer: store entry t-1 (h(t-1) in Abuf[cur]), L2-resident ----
        if constexpr (PROD) {
            if (t >= 1) {
                const int e = t - 1;
                if ((e & 3) == 0 && e + 4 > RSLOT && cpend < e + 4 - RSLOT)
                    cpend = flag_spin(cin_flag, e + 4 - RSLOT);       // rare
                u64 hv = *(const u64*)&Abuf[cur][HB0 + tid * 4];
                __hip_atomic_store(rout + (e & (RSLOT - 1)) * 512 + tid, hv,
                                   __ATOMIC_RELAXED, __HIP_MEMORY_SCOPE_WORKGROUP);
                if ((e & 3) == 1) cpend = flag_peek(cin_flag);        // deferred refresh
            }
        }

        // ---- prefetch x(t+2) (MODE 0) ----
        float pfx1 = 0.0f;
        if constexpr (!CONS) {
            if (t + 2 < TLEN) {
                const int m = tid >> 5, k = tid & 31;
                if (k < DINL) pfx1 = xin[((bbase + m) * TLEN + (t + 2)) * DINL + k];
            }
        }

        // ---- gates = A @ W^T (fp32 accum, bias pre-loaded into acc) ----
        f32x4 acc[4];
#pragma unroll
        for (int g = 0; g < 4; ++g) {
            f32x4 bi = {bb[g], bb[g], bb[g], bb[g]};
            acc[g] = bi;
        }
#pragma unroll
        for (int kt = 0; kt < NKT; ++kt) {
            bf16x8 a = *(const bf16x8*)&Abuf[cur][kt * 512 + lane * 8];
#pragma unroll
            for (int g = 0; g < 4; ++g)
                acc[g] = __builtin_amdgcn_mfma_f32_16x16x32_bf16(a, Wf[g][kt], acc[g], 0, 0, 0);
        }

        // ---- in-lane LSTM cell update ----
        unsigned short hb[4]; float hf[4];
#pragma unroll
        for (int r = 0; r < 4; ++r) {
            const float iv = sig_ps (acc[0][r]);
            const float fv = sig_ps (acc[1][r]);
            const float gv = tanh_ps(acc[2][r]);
            const float ov = sig_ps (acc[3][r]);
            const float c  = fv * cst[r] + iv * gv;
            cst[r] = c;
            const float h  = ov * tanh_ps(c * LOG2E2);
            hf[r] = h;
            hb[r] = f2bf_fast(h);
        }

        // ---- h -> Abuf[nxt] h-region (A-layout, own recurrence) ----
        {
            const int j  = wave * 16 + n16;
            const int kh = KX + j;
            const int kt = kh >> 5, kk = kh & 31;
            const int eb = kt * 512 + (kk >> 3) * 128 + (kk & 7);
#pragma unroll
            for (int r = 0; r < 4; ++r)
                Abuf[nxt][eb + (quad * 4 + r) * 8] = hb[r];
        }
        if constexpr (WFC) {
            if (t == TLEN - 1)
#pragma unroll
                for (int r = 0; r < 4; ++r)
                    fcred[(quad * 4 + r) * HID + wave * 16 + n16] = hf[r];
        }

        // ---- commit entry t+1 into Abuf[nxt] x-region; shift queue ----
        if (t + 1 < TLEN) {
            if constexpr (CONS) {
                *(u64*)&Abuf[nxt][tid * 4] = q[0];
#pragma unroll
                for (int i = 0; i < QD - 2; ++i) q[i] = q[i + 1];
                q[QD - 2] = qn;
            } else {
                const int m = tid >> 5, k = tid & 31;
                Abuf[nxt][((k >> 3) * 16 + m) * 8 + (k & 7)] = f2bf(pfx0);
                pfx0 = pfx1;
            }
        }
    }

    // ---- producer epilogue: flush entry T-1, final flags ----
    if constexpr (PROD) {
        __syncthreads();   // h(T-1) in Abuf[TLEN&1]; step T-1 stores drained
        if (tid == 0)
            __hip_atomic_store(pout_flag, TLEN - 1, __ATOMIC_RELAXED, __HIP_MEMORY_SCOPE_AGENT);
        {
            flag_spin(cin_flag, TLEN - RSLOT);
            u64 hv = *(const u64*)&Abuf[TLEN & 1][HB0 + tid * 4];
            __hip_atomic_store(rout + ((TLEN - 1) & (RSLOT - 1)) * 512 + tid, hv,
                               __ATOMIC_RELAXED, __HIP_MEMORY_SCOPE_WORKGROUP);
        }
        __syncthreads();   // drain entry T-1 stores into L2
        if (tid == 0)
            __hip_atomic_store(pout_flag, TLEN, __ATOMIC_RELAXED, __HIP_MEMORY_SCOPE_AGENT);
    }
}

extern "C" __global__ __launch_bounds__(512, 2)
void lstm3_pipe_kernel(const float* __restrict__ xin,
    const float* __restrict__ wih0, const float* __restrict__ whh0,
    const float* __restrict__ bih0, const float* __restrict__ bhh0,
    const float* __restrict__ wih1, const float* __restrict__ whh1,
    const float* __restrict__ bih1, const float* __restrict__ bhh1,
    const float* __restrict__ wih2, const float* __restrict__ whh2,
    const float* __restrict__ bih2, const float* __restrict__ bhh2,
    const float* __restrict__ fcw, const float* __restrict__ fcb,
    float* __restrict__ out,
    int* __restrict__ flags, u64* __restrict__ ring0, u64* __restrict__ ring1)
{
    __shared__ unsigned short Abuf[2][8 * 512];   // 16 KB
    __shared__ float fcred[16 * HID];             // 8 KB

    const int tid   = threadIdx.x;
    const int wave  = tid >> 6;
    const int lane  = tid & 63;
    const int n16   = lane & 15;
    const int quad  = lane >> 4;

    // bid = ((s>>3)*3 + layer)*8 + (s&7): all 3 stages of slice s on one XCD
    const int xcd    = blockIdx.x & 7;
    const int grp    = blockIdx.x >> 3;       // 0..23
    const int layer  = grp % 3;
    const int sgroup = grp / 3;               // 0..7
    const int slice  = sgroup * 8 + xcd;
    const int bbase  = slice * 16;

    u64* r0 = ring0 + (size_t)slice * (RSLOT * 512);
    u64* r1 = ring1 + (size_t)slice * (RSLOT * 512);
    // each flag on its own 256 B line
    int* prod0 = flags + (size_t)(0 * 64 + slice) * 64;
    int* prod1 = flags + (size_t)(1 * 64 + slice) * 64;
    int* cons1 = flags + (size_t)(2 * 64 + slice) * 64;
    int* cons2 = flags + (size_t)(3 * 64 + slice) * 64;

    if (layer == 0) {
        run_layer_p<0, false, true, false>(xin, nullptr, r0,
            nullptr, nullptr, cons1, prod0,
            wih0, whh0, bih0, bhh0, Abuf, fcred, tid, wave, lane, n16, quad, bbase);
    } else if (layer == 1) {
        run_layer_p<1, true, true, false>(nullptr, r0, r1,
            prod0, cons1, cons2, prod1,
            wih1, whh1, bih1, bhh1, Abuf, fcred, tid, wave, lane, n16, quad, bbase);
    } else {
        run_layer_p<1, true, false, true>(nullptr, r1, nullptr,
            prod1, cons2, nullptr, nullptr,
            wih2, whh2, bih2, bhh2, Abuf, fcred, tid, wave, lane, n16, quad, bbase);
        __syncthreads();
        if (tid < 16) {
            float s = 0.0f;
#pragma unroll 8
            for (int j = 0; j < HID; ++j) s += fcw[j] * fcred[tid * HID + j];
            out[bbase + tid] = s + fcb[0];
        }
    }
}

extern "C" void kernel_launch(void* const* d_in, const int* in_sizes, int n_in,
                              void* d_out, int out_size, void* d_ws, size_t ws_size,
                              hipStream_t stream) {
    (void)in_sizes; (void)n_in; (void)out_size; (void)ws_size;
    const float* x    = (const float*)d_in[0];
    const float* wih0 = (const float*)d_in[1];
    const float* whh0 = (const float*)d_in[2];
    const float* bih0 = (const float*)d_in[3];
    const float* bhh0 = (const float*)d_in[4];
    const float* wih1 = (const float*)d_in[5];
    const float* whh1 = (const float*)d_in[6];
    const float* bih1 = (const float*)d_in[7];
    const float* bhh1 = (const float*)d_in[8];
    const float* wih2 = (const float*)d_in[9];
    const float* whh2 = (const float*)d_in[10];
    const float* bih2 = (const float*)d_in[11];
    const float* bhh2 = (const float*)d_in[12];
    const float* fcw  = (const float*)d_in[13];
    const float* fcb  = (const float*)d_in[14];
    float* out = (float*)d_out;

    // ws: flags 64 KB (poison-negative = not ready), ring0 4 MB, ring1 4 MB
    int* flags = (int*)d_ws;
    u64* ring0 = (u64*)((char*)d_ws + 65536);
    u64* ring1 = ring0 + (size_t)64 * RSLOT * 512;

    lstm3_pipe_kernel<<<dim3(192), dim3(512), 0, stream>>>(
        x, wih0, whh0, bih0, bhh0, wih1, whh1, bih1, bhh1,
        wih2, whh2, bih2, bhh2, fcw, fcb, out, flags, ring0, ring1);
}

// Round 10
// 838.002 us; speedup vs baseline: 1.1338x; 1.0562x over previous
//
#include <hip/hip_runtime.h>

#define TLEN  512
#define HID   128
#define RSLOT 16   // ring slots/slice; per-XCD live set ~1 MB (L2-resident)
#define QD    4    // consumer prefetch distance

typedef __attribute__((ext_vector_type(8))) short          bf16x8;
typedef __attribute__((ext_vector_type(4))) float          f32x4;
typedef __attribute__((ext_vector_type(4))) unsigned short u16x4;
typedef unsigned long long u64;

#define LOG2E  1.4426950408889634f
#define LOG2E2 2.8853900817779268f

// RNE (cold paths: weights, x staging)
__device__ __forceinline__ unsigned short f2bf(float f) {
    union { float f; unsigned u; } v; v.f = f;
    unsigned r = v.u + 0x7fffu + ((v.u >> 16) & 1u);
    return (unsigned short)(r >> 16);
}
// round-half-up (hot path: h)
__device__ __forceinline__ unsigned short f2bf_fast(float f) {
    union { float f; unsigned u; } v; v.f = f;
    return (unsigned short)((v.u + 0x8000u) >> 16);
}

__device__ __forceinline__ float sig_ps(float xs) {
    return __builtin_amdgcn_rcpf(1.0f + __builtin_exp2f(-xs));
}
__device__ __forceinline__ float tanh_ps(float xs) {
    return 2.0f * __builtin_amdgcn_rcpf(1.0f + __builtin_exp2f(-xs)) - 1.0f;
}

// Loads: AGENT scope (L1-bypass -> served by the XCD's L2).
// Stores: WORKGROUP scope (dirty in local L2, ~200cyc ack — NOT L3 write-through).
// Same-XCD placement (below) makes this correct; proven by R9's ring data.
__device__ __forceinline__ int flag_peek(const int* f) {
    return __hip_atomic_load(f, __ATOMIC_RELAXED, __HIP_MEMORY_SCOPE_AGENT);
}
__device__ __forceinline__ int flag_spin(const int* f, int v) {
    int x = flag_peek(f);
    while (x < v) { __builtin_amdgcn_s_sleep(1); x = flag_peek(f); }
    return x;
}
__device__ __forceinline__ void flag_pub(int* f, int v) {
    __hip_atomic_store(f, v, __ATOMIC_RELAXED, __HIP_MEMORY_SCOPE_WORKGROUP);
}

// One LSTM layer over T steps for a 16-row batch slice. Uniform 8-wave block.
// All cross-stage comm (ring data AND flags) lives in the same XCD's L2:
// stages of slice s placed via bid = ((s>>3)*3 + layer)*8 + (s&7) (bid&7->XCD).
template<int MODE, bool CONS, bool PROD, bool WFC>
__device__ __forceinline__ void run_layer_p(
    const float* __restrict__ xin,
    const u64* __restrict__ rin, u64* __restrict__ rout,
    const int* pin_flag, int* cout_flag, const int* cin_flag, int* pout_flag,
    const float* __restrict__ wih, const float* __restrict__ whh,
    const float* __restrict__ bih, const float* __restrict__ bhh,
    unsigned short (* __restrict__ Abuf)[8 * 512],
    float* __restrict__ fcred,
    const int tid, const int wave, const int lane,
    const int n16, const int quad, const int bbase)
{
    constexpr int NKT  = MODE ? 8 : 5;      // K-tiles of 32
    constexpr int KX   = MODE ? 128 : 32;   // padded x-region width
    constexpr int DINL = MODE ? 128 : 6;    // real input features
    constexpr int HB0  = MODE ? 2048 : 512; // h-region start elem

    // ---- weights -> register/AGPR B fragments (prescaled) ----
    bf16x8 Wf[4][NKT];
    float  bb[4];
#pragma unroll
    for (int g = 0; g < 4; ++g) {
        const float sc = (g == 2) ? LOG2E2 : LOG2E;
        const int row = g * 128 + wave * 16 + n16;
        bb[g] = (bih[row] + bhh[row]) * sc;
#pragma unroll
        for (int kt = 0; kt < NKT; ++kt) {
            const int kbase = kt * 32 + quad * 8;
            bf16x8 wv;
#pragma unroll
            for (int j = 0; j < 8; ++j) {
                const int k = kbase + j;
                float f;
                if (k < KX) f = (k < DINL) ? wih[row * DINL + k] : 0.0f;
                else        f = whh[row * HID + (k - KX)];
                wv[j] = (short)f2bf(f * sc);
            }
            Wf[g][kt] = wv;
        }
    }

    // ---- prologue: zero h-region; entry 0 -> LDS, entries 1..QD-1 -> queue ----
    { u16x4 z = {0, 0, 0, 0}; *(u16x4*)&Abuf[0][HB0 + tid * 4] = z; }
    u64 q[QD - 1]; u64 qn = 0;
#pragma unroll
    for (int i = 0; i < QD - 1; ++i) q[i] = 0;
    float pfx0 = 0.0f;
    int pend = 0, cpend = 0;
    if constexpr (CONS) {
        flag_spin(pin_flag, 1);
        u64 v0 = __hip_atomic_load(rin + tid, __ATOMIC_RELAXED, __HIP_MEMORY_SCOPE_AGENT);
        *(u64*)&Abuf[0][tid * 4] = v0;
        pend = flag_spin(pin_flag, QD);
#pragma unroll
        for (int i = 0; i < QD - 1; ++i)
            q[i] = __hip_atomic_load(rin + (i + 1) * 512 + tid, __ATOMIC_RELAXED, __HIP_MEMORY_SCOPE_AGENT);
    } else {
        const int m = tid >> 5, k = tid & 31;
        float v = (k < DINL) ? xin[((bbase + m) * TLEN + 0) * DINL + k] : 0.0f;
        Abuf[0][((k >> 3) * 16 + m) * 8 + (k & 7)] = f2bf(v);
        if (k < DINL) pfx0 = xin[((bbase + m) * TLEN + 1) * DINL + k];
    }
    if constexpr (PROD) cpend = -(1 << 30);   // force first real check to spin

    float cst[4] = {0.f, 0.f, 0.f, 0.f};

    for (int t = 0; t < TLEN; ++t) {
        const int cur = t & 1, nxt = cur ^ 1;
        __syncthreads();   // Abuf[cur] ready; all vmem drained (vmcnt(0))

        // ---- ring load of entry t+QD (longest pole — issue first) ----
        if constexpr (CONS) {
            if (t + QD < TLEN) {
                if (pend < t + QD + 1) pend = flag_spin(pin_flag, t + QD + 1);  // rare
                qn = __hip_atomic_load(rin + ((t + QD) & (RSLOT - 1)) * 512 + tid,
                                       __ATOMIC_RELAXED, __HIP_MEMORY_SCOPE_AGENT);
                pend = flag_peek(pin_flag);   // deferred refresh, used next step
            }
        }

        // ---- publish progress (workgroup scope: local-L2 ack, no L3 trip) ----
        if (tid == 0) {
            if constexpr (CONS)   // backpressure-only: amortize 1-in-4
                if ((t & 3) == 0)
                    flag_pub(cout_flag, t + QD);
            if constexpr (PROD)   // critical chain: every step
                if (t >= 2)
                    flag_pub(pout_flag, t - 1);
        }

        // ---- producer: store entry t-1 (h(t-1) in Abuf[cur]), L2-resident ----
        if constexpr (PROD) {
            if (t >= 1) {
                const int e = t - 1;
                if ((e & 3) == 0 && e + 4 > RSLOT && cpend < e + 4 - RSLOT)
                    cpend = flag_spin(cin_flag, e + 4 - RSLOT);       // rare
                u64 hv = *(const u64*)&Abuf[cur][HB0 + tid * 4];
                __hip_atomic_store(rout + (e & (RSLOT - 1)) * 512 + tid, hv,
                                   __ATOMIC_RELAXED, __HIP_MEMORY_SCOPE_WORKGROUP);
                if ((e & 3) == 1) cpend = flag_peek(cin_flag);        // deferred refresh
            }
        }

        // ---- prefetch x(t+2) (MODE 0) ----
        float pfx1 = 0.0f;
        if constexpr (!CONS) {
            if (t + 2 < TLEN) {
                const int m = tid >> 5, k = tid & 31;
                if (k < DINL) pfx1 = xin[((bbase + m) * TLEN + (t + 2)) * DINL + k];
            }
        }

        // ---- gates = A @ W^T (fp32 accum, bias pre-loaded into acc) ----
        f32x4 acc[4];
#pragma unroll
        for (int g = 0; g < 4; ++g) {
            f32x4 bi = {bb[g], bb[g], bb[g], bb[g]};
            acc[g] = bi;
        }
#pragma unroll
        for (int kt = 0; kt < NKT; ++kt) {
            bf16x8 a = *(const bf16x8*)&Abuf[cur][kt * 512 + lane * 8];
#pragma unroll
            for (int g = 0; g < 4; ++g)
                acc[g] = __builtin_amdgcn_mfma_f32_16x16x32_bf16(a, Wf[g][kt], acc[g], 0, 0, 0);
        }

        // ---- in-lane LSTM cell update ----
        unsigned short hb[4]; float hf[4];
#pragma unroll
        for (int r = 0; r < 4; ++r) {
            const float iv = sig_ps (acc[0][r]);
            const float fv = sig_ps (acc[1][r]);
            const float gv = tanh_ps(acc[2][r]);
            const float ov = sig_ps (acc[3][r]);
            const float c  = fv * cst[r] + iv * gv;
            cst[r] = c;
            const float h  = ov * tanh_ps(c * LOG2E2);
            hf[r] = h;
            hb[r] = f2bf_fast(h);
        }

        // ---- h -> Abuf[nxt] h-region (A-layout, own recurrence) ----
        {
            const int j  = wave * 16 + n16;
            const int kh = KX + j;
            const int kt = kh >> 5, kk = kh & 31;
            const int eb = kt * 512 + (kk >> 3) * 128 + (kk & 7);
#pragma unroll
            for (int r = 0; r < 4; ++r)
                Abuf[nxt][eb + (quad * 4 + r) * 8] = hb[r];
        }
        if constexpr (WFC) {
            if (t == TLEN - 1)
#pragma unroll
                for (int r = 0; r < 4; ++r)
                    fcred[(quad * 4 + r) * HID + wave * 16 + n16] = hf[r];
        }

        // ---- commit entry t+1 into Abuf[nxt] x-region; shift queue ----
        if (t + 1 < TLEN) {
            if constexpr (CONS) {
                *(u64*)&Abuf[nxt][tid * 4] = q[0];
#pragma unroll
                for (int i = 0; i < QD - 2; ++i) q[i] = q[i + 1];
                q[QD - 2] = qn;
            } else {
                const int m = tid >> 5, k = tid & 31;
                Abuf[nxt][((k >> 3) * 16 + m) * 8 + (k & 7)] = f2bf(pfx0);
                pfx0 = pfx1;
            }
        }
    }

    // ---- producer epilogue: flush entry T-1, final flags ----
    if constexpr (PROD) {
        __syncthreads();   // h(T-1) in Abuf[TLEN&1]; step T-1 stores drained
        if (tid == 0)
            flag_pub(pout_flag, TLEN - 1);
        {
            flag_spin(cin_flag, TLEN - RSLOT);
            u64 hv = *(const u64*)&Abuf[TLEN & 1][HB0 + tid * 4];
            __hip_atomic_store(rout + ((TLEN - 1) & (RSLOT - 1)) * 512 + tid, hv,
                               __ATOMIC_RELAXED, __HIP_MEMORY_SCOPE_WORKGROUP);
        }
        __syncthreads();   // drain entry T-1 stores into L2
        if (tid == 0)
            flag_pub(pout_flag, TLEN);
    }
}

extern "C" __global__ __launch_bounds__(512, 2)
void lstm3_pipe_kernel(const float* __restrict__ xin,
    const float* __restrict__ wih0, const float* __restrict__ whh0,
    const float* __restrict__ bih0, const float* __restrict__ bhh0,
    const float* __restrict__ wih1, const float* __restrict__ whh1,
    const float* __restrict__ bih1, const float* __restrict__ bhh1,
    const float* __restrict__ wih2, const float* __restrict__ whh2,
    const float* __restrict__ bih2, const float* __restrict__ bhh2,
    const float* __restrict__ fcw, const float* __restrict__ fcb,
    float* __restrict__ out,
    int* __restrict__ flags, u64* __restrict__ ring0, u64* __restrict__ ring1)
{
    __shared__ unsigned short Abuf[2][8 * 512];   // 16 KB
    __shared__ float fcred[16 * HID];             // 8 KB

    const int tid   = threadIdx.x;
    const int wave  = tid >> 6;
    const int lane  = tid & 63;
    const int n16   = lane & 15;
    const int quad  = lane >> 4;

    // bid = ((s>>3)*3 + layer)*8 + (s&7): all 3 stages of slice s on one XCD
    const int xcd    = blockIdx.x & 7;
    const int grp    = blockIdx.x >> 3;       // 0..23
    const int layer  = grp % 3;
    const int sgroup = grp / 3;               // 0..7
    const int slice  = sgroup * 8 + xcd;
    const int bbase  = slice * 16;

    u64* r0 = ring0 + (size_t)slice * (RSLOT * 512);
    u64* r1 = ring1 + (size_t)slice * (RSLOT * 512);
    // each flag on its own 256 B line
    int* prod0 = flags + (size_t)(0 * 64 + slice) * 64;
    int* prod1 = flags + (size_t)(1 * 64 + slice) * 64;
    int* cons1 = flags + (size_t)(2 * 64 + slice) * 64;
    int* cons2 = flags + (size_t)(3 * 64 + slice) * 64;

    if (layer == 0) {
        run_layer_p<0, false, true, false>(xin, nullptr, r0,
            nullptr, nullptr, cons1, prod0,
            wih0, whh0, bih0, bhh0, Abuf, fcred, tid, wave, lane, n16, quad, bbase);
    } else if (layer == 1) {
        run_layer_p<1, true, true, false>(nullptr, r0, r1,
            prod0, cons1, cons2, prod1,
            wih1, whh1, bih1, bhh1, Abuf, fcred, tid, wave, lane, n16, quad, bbase);
    } else {
        run_layer_p<1, true, false, true>(nullptr, r1, nullptr,
            prod1, cons2, nullptr, nullptr,
            wih2, whh2, bih2, bhh2, Abuf, fcred, tid, wave, lane, n16, quad, bbase);
        __syncthreads();
        if (tid < 16) {
            float s = 0.0f;
#pragma unroll 8
            for (int j = 0; j < HID; ++j) s += fcw[j] * fcred[tid * HID + j];
            out[bbase + tid] = s + fcb[0];
        }
    }
}

extern "C" void kernel_launch(void* const* d_in, const int* in_sizes, int n_in,
                              void* d_out, int out_size, void* d_ws, size_t ws_size,
                              hipStream_t stream) {
    (void)in_sizes; (void)n_in; (void)out_size; (void)ws_size;
    const float* x    = (const float*)d_in[0];
    const float* wih0 = (const float*)d_in[1];
    const float* whh0 = (const float*)d_in[2];
    const float* bih0 = (const float*)d_in[3];
    const float* bhh0 = (const float*)d_in[4];
    const float* wih1 = (const float*)d_in[5];
    const float* whh1 = (const float*)d_in[6];
    const float* bih1 = (const float*)d_in[7];
    const float* bhh1 = (const float*)d_in[8];
    const float* wih2 = (const float*)d_in[9];
    const float* whh2 = (const float*)d_in[10];
    const float* bih2 = (const float*)d_in[11];
    const float* bhh2 = (const float*)d_in[12];
    const float* fcw  = (const float*)d_in[13];
    const float* fcb  = (const float*)d_in[14];
    float* out = (float*)d_out;

    // ws: flags 64 KB (poison-negative = not ready), ring0 4 MB, ring1 4 MB
    int* flags = (int*)d_ws;
    u64* ring0 = (u64*)((char*)d_ws + 65536);
    u64* ring1 = ring0 + (size_t)64 * RSLOT * 512;

    lstm3_pipe_kernel<<<dim3(192), dim3(512), 0, stream>>>(
        x, wih0, whh0, bih0, bhh0, wih1, whh1, bih1, bhh1,
        wih2, whh2, bih2, bhh2, fcw, fcb, out, flags, ring0, ring1);
}

// Round 11
// 833.637 us; speedup vs baseline: 1.1398x; 1.0052x over previous
//
#include <hip/hip_runtime.h>

#define TLEN  512
#define HID   128
#define RSLOT 16   // ring slots/slice (L2-resident live set)

typedef __attribute__((ext_vector_type(8))) short          bf16x8;
typedef __attribute__((ext_vector_type(4))) float          f32x4;
typedef __attribute__((ext_vector_type(4))) unsigned short u16x4;
typedef unsigned long long u64;

#define LOG2E  1.4426950408889634f
#define LOG2E2 2.8853900817779268f

// RNE (cold paths)
__device__ __forceinline__ unsigned short f2bf(float f) {
    union { float f; unsigned u; } v; v.f = f;
    unsigned r = v.u + 0x7fffu + ((v.u >> 16) & 1u);
    return (unsigned short)(r >> 16);
}
// round-half-up (hot path: h)
__device__ __forceinline__ unsigned short f2bf_fast(float f) {
    union { float f; unsigned u; } v; v.f = f;
    return (unsigned short)((v.u + 0x8000u) >> 16);
}

__device__ __forceinline__ float sig_ps(float xs) {
    return __builtin_amdgcn_rcpf(1.0f + __builtin_exp2f(-xs));
}
__device__ __forceinline__ float tanh_ps(float xs) {
    return 2.0f * __builtin_amdgcn_rcpf(1.0f + __builtin_exp2f(-xs)) - 1.0f;
}

// Loads AGENT scope (L1-bypass -> same-XCD L2); stores WORKGROUP scope
// (dirty in local L2). Same-XCD placement makes this correct (R9/R10 proven).
__device__ __forceinline__ int flag_peek(const int* f) {
    return __hip_atomic_load(f, __ATOMIC_RELAXED, __HIP_MEMORY_SCOPE_AGENT);
}
__device__ __forceinline__ int flag_spin(const int* f, int v) {
    int x = flag_peek(f);
    while (x < v) { __builtin_amdgcn_s_sleep(1); x = flag_peek(f); }
    return x;
}
__device__ __forceinline__ void flag_pub(int* f, int v) {
    __hip_atomic_store(f, v, __ATOMIC_RELAXED, __HIP_MEMORY_SCOPE_WORKGROUP);
}

// Split-GEMM LSTM layer: gates(t) = xacc(t) + h(t-1)@W_hh.
// xacc(t+1) (bias + x(t+1)@W_ih) is pre-computed in the SHADOW of step t from
// a triple-buffered LDS x region (x(t+2) committed at step t). Critical path
// per step = 4 ds_read_b128 -> 16 MFMA -> activations -> h write.
// hbuf: 2 x 2048 bf16 (h fragment order, K=128). xbuf: 3 x 2048 (MODE0: 512).
// Ring entry order == h fragment order == consumer x-commit order.
template<int MODE, bool CONS, bool PROD, bool WFC>
__device__ __forceinline__ void run_layer_p(
    const float* __restrict__ xin,
    const u64* __restrict__ rin, u64* __restrict__ rout,
    const int* pin_flag, int* cout_flag, const int* cin_flag, int* pout_flag,
    const float* __restrict__ wih, const float* __restrict__ whh,
    const float* __restrict__ bih, const float* __restrict__ bhh,
    unsigned short (* __restrict__ hbuf)[2048],
    unsigned short (* __restrict__ xbuf)[2048],
    float* __restrict__ fcred,
    const int tid, const int wave, const int lane,
    const int n16, const int quad, const int bbase)
{
    constexpr int NKTX = MODE ? 4 : 1;    // x K-tiles of 32
    constexpr int DINL = MODE ? 128 : 6;  // real input features

    // ---- weights -> register B fragments (prescaled) ----
    bf16x8 Wfx[4][NKTX], Wfh[4][4];
    float  bb[4];
#pragma unroll
    for (int g = 0; g < 4; ++g) {
        const float sc = (g == 2) ? LOG2E2 : LOG2E;
        const int row = g * 128 + wave * 16 + n16;
        bb[g] = (bih[row] + bhh[row]) * sc;
#pragma unroll
        for (int kt = 0; kt < NKTX; ++kt) {
            bf16x8 wv;
#pragma unroll
            for (int j = 0; j < 8; ++j) {
                const int k = kt * 32 + quad * 8 + j;
                wv[j] = (short)f2bf(((k < DINL) ? wih[row * DINL + k] : 0.0f) * sc);
            }
            Wfx[g][kt] = wv;
        }
#pragma unroll
        for (int kt = 0; kt < 4; ++kt) {
            bf16x8 wv;
#pragma unroll
            for (int j = 0; j < 8; ++j) {
                const int k = kt * 32 + quad * 8 + j;
                wv[j] = (short)f2bf(whh[row * HID + k] * sc);
            }
            Wfh[g][kt] = wv;
        }
    }

    // ---- prologue ----
    { u16x4 z = {0, 0, 0, 0}; *(u16x4*)&hbuf[0][tid * 4] = z; }   // h(-1)=0
    u64 q0 = 0, q1 = 0, q2 = 0, qn = 0;
    float pfx0 = 0.0f;
    int pend = 0, cpend = 0;
    const int xm = tid >> 5, xk = tid & 31;                        // MODE0 commit map
    if constexpr (CONS) {
        // commit entries 0,1 -> xbuf[0],xbuf[1]; queue entries 2..4
        flag_spin(pin_flag, 1);
        *(u64*)&xbuf[0][tid * 4] =
            __hip_atomic_load(rin + tid, __ATOMIC_RELAXED, __HIP_MEMORY_SCOPE_AGENT);
        flag_spin(pin_flag, 2);
        *(u64*)&xbuf[1][tid * 4] =
            __hip_atomic_load(rin + 512 + tid, __ATOMIC_RELAXED, __HIP_MEMORY_SCOPE_AGENT);
        pend = flag_spin(pin_flag, 5);
        q0 = __hip_atomic_load(rin + 2 * 512 + tid, __ATOMIC_RELAXED, __HIP_MEMORY_SCOPE_AGENT);
        q1 = __hip_atomic_load(rin + 3 * 512 + tid, __ATOMIC_RELAXED, __HIP_MEMORY_SCOPE_AGENT);
        q2 = __hip_atomic_load(rin + 4 * 512 + tid, __ATOMIC_RELAXED, __HIP_MEMORY_SCOPE_AGENT);
    } else {
        // commit x(0),x(1); prefetch x(2)
        const int ei = ((xk >> 3) * 16 + xm) * 8 + (xk & 7);
        float v0 = (xk < DINL) ? xin[((bbase + xm) * TLEN + 0) * DINL + xk] : 0.0f;
        float v1 = (xk < DINL) ? xin[((bbase + xm) * TLEN + 1) * DINL + xk] : 0.0f;
        xbuf[0][ei] = f2bf(v0);
        xbuf[1][ei] = f2bf(v1);
        if (xk < DINL) pfx0 = xin[((bbase + xm) * TLEN + 2) * DINL + xk];
    }
    if constexpr (PROD) cpend = -(1 << 30);
    __syncthreads();   // xbuf[0..1], hbuf[0] visible

    // xacc(0) = bias + x(0)@Wx
    f32x4 accA[4], accB[4];
#pragma unroll
    for (int g = 0; g < 4; ++g) { f32x4 bi = {bb[g], bb[g], bb[g], bb[g]}; accA[g] = bi; }
#pragma unroll
    for (int kt = 0; kt < NKTX; ++kt) {
        bf16x8 a = *(const bf16x8*)&xbuf[0][kt * 512 + lane * 8];
#pragma unroll
        for (int g = 0; g < 4; ++g)
            accA[g] = __builtin_amdgcn_mfma_f32_16x16x32_bf16(a, Wfx[g][kt], accA[g], 0, 0, 0);
    }

    float cst[4] = {0.f, 0.f, 0.f, 0.f};
    int rd = 1, wr = 2;   // at step t: rd=(t+1)%3 (shadow read), wr=(t+2)%3 (commit)

    auto step = [&](f32x4 (&accC)[4], f32x4 (&accN)[4], int t) {
        const int cur = t & 1, nxt = cur ^ 1;
        __syncthreads();   // hbuf[cur], xbuf[rd] ready; all vmem drained

        // ---- shadow: ring load entry t+5 ----
        if constexpr (CONS) {
            if (t + 5 < TLEN) {
                if (pend < t + 6) pend = flag_spin(pin_flag, t + 6);   // rare
                qn = __hip_atomic_load(rin + ((t + 5) & (RSLOT - 1)) * 512 + tid,
                                       __ATOMIC_RELAXED, __HIP_MEMORY_SCOPE_AGENT);
                pend = flag_peek(pin_flag);
            }
        }
        // ---- publish progress ----
        if (tid == 0) {
            if constexpr (CONS) if ((t & 3) == 0) flag_pub(cout_flag, t + 5);
            if constexpr (PROD) if (t >= 2)       flag_pub(pout_flag, t - 1);
        }
        // ---- producer: store entry t-1 (h(t-1) in hbuf[cur]) ----
        if constexpr (PROD) {
            if (t >= 1) {
                const int e = t - 1;
                if ((e & 3) == 0 && e + 4 > RSLOT && cpend < e + 4 - RSLOT)
                    cpend = flag_spin(cin_flag, e + 4 - RSLOT);        // rare
                u64 hv = *(const u64*)&hbuf[cur][tid * 4];
                __hip_atomic_store(rout + (e & (RSLOT - 1)) * 512 + tid, hv,
                                   __ATOMIC_RELAXED, __HIP_MEMORY_SCOPE_WORKGROUP);
                if ((e & 3) == 1) cpend = flag_peek(cin_flag);
            }
        }
        // ---- shadow: global x prefetch (MODE0) ----
        float pfx1 = 0.0f;
        if constexpr (!CONS) {
            if (t + 3 < TLEN && xk < DINL)
                pfx1 = xin[((bbase + xm) * TLEN + (t + 3)) * DINL + xk];
        }

        // ---- CRITICAL: gates = xacc(t) + h(t-1)@W_hh ----
#pragma unroll
        for (int kt = 0; kt < 4; ++kt) {
            bf16x8 a = *(const bf16x8*)&hbuf[cur][kt * 512 + lane * 8];
#pragma unroll
            for (int g = 0; g < 4; ++g)
                accC[g] = __builtin_amdgcn_mfma_f32_16x16x32_bf16(a, Wfh[g][kt], accC[g], 0, 0, 0);
        }

        // ---- SHADOW: xacc(t+1) = bias + x(t+1)@W_ih ----
        if (t + 1 < TLEN) {
#pragma unroll
            for (int g = 0; g < 4; ++g) { f32x4 bi = {bb[g], bb[g], bb[g], bb[g]}; accN[g] = bi; }
#pragma unroll
            for (int kt = 0; kt < NKTX; ++kt) {
                bf16x8 a = *(const bf16x8*)&xbuf[rd][kt * 512 + lane * 8];
#pragma unroll
                for (int g = 0; g < 4; ++g)
                    accN[g] = __builtin_amdgcn_mfma_f32_16x16x32_bf16(a, Wfx[g][kt], accN[g], 0, 0, 0);
            }
        }

        // ---- in-lane LSTM cell update ----
        unsigned short hb[4]; float hf[4];
#pragma unroll
        for (int r = 0; r < 4; ++r) {
            const float iv = sig_ps (accC[0][r]);
            const float fv = sig_ps (accC[1][r]);
            const float gv = tanh_ps(accC[2][r]);
            const float ov = sig_ps (accC[3][r]);
            const float c  = fv * cst[r] + iv * gv;
            cst[r] = c;
            const float h  = ov * tanh_ps(c * LOG2E2);
            hf[r] = h;
            hb[r] = f2bf_fast(h);
        }
        // ---- h -> hbuf[nxt] (fragment order) ----
        {
            const int j  = wave * 16 + n16;
            const int eb = (j >> 5) * 512 + (((j & 31) >> 3) * 16) * 8 + ((j & 31) & 7);
#pragma unroll
            for (int r = 0; r < 4; ++r)
                hbuf[nxt][eb + (quad * 4 + r) * 8] = hb[r];
        }
        if constexpr (WFC) {
            if (t == TLEN - 1)
#pragma unroll
                for (int r = 0; r < 4; ++r)
                    fcred[(quad * 4 + r) * HID + wave * 16 + n16] = hf[r];
        }
        // ---- commit x(t+2) -> xbuf[wr]; shift queue ----
        if (t + 2 < TLEN) {
            if constexpr (CONS) {
                *(u64*)&xbuf[wr][tid * 4] = q0;
                q0 = q1; q1 = q2; q2 = qn;
            } else {
                xbuf[wr][((xk >> 3) * 16 + xm) * 8 + (xk & 7)] = f2bf(pfx0);
                pfx0 = pfx1;
            }
        }
        rd = wr; wr = (wr == 2) ? 0 : wr + 1;
    };

    for (int t = 0; t < TLEN; t += 2) {
        step(accA, accB, t);
        step(accB, accA, t + 1);
    }

    // ---- producer epilogue: flush entry T-1 ----
    if constexpr (PROD) {
        __syncthreads();   // h(T-1) in hbuf[0]; step T-1 stores drained
        if (tid == 0) flag_pub(pout_flag, TLEN - 1);
        {
            flag_spin(cin_flag, TLEN - RSLOT);
            u64 hv = *(const u64*)&hbuf[TLEN & 1][tid * 4];
            __hip_atomic_store(rout + ((TLEN - 1) & (RSLOT - 1)) * 512 + tid, hv,
                               __ATOMIC_RELAXED, __HIP_MEMORY_SCOPE_WORKGROUP);
        }
        __syncthreads();
        if (tid == 0) flag_pub(pout_flag, TLEN);
    }
}

extern "C" __global__ __launch_bounds__(512, 1)
void lstm3_pipe_kernel(const float* __restrict__ xin,
    const float* __restrict__ wih0, const float* __restrict__ whh0,
    const float* __restrict__ bih0, const float* __restrict__ bhh0,
    const float* __restrict__ wih1, const float* __restrict__ whh1,
    const float* __restrict__ bih1, const float* __restrict__ bhh1,
    const float* __restrict__ wih2, const float* __restrict__ whh2,
    const float* __restrict__ bih2, const float* __restrict__ bhh2,
    const float* __restrict__ fcw, const float* __restrict__ fcb,
    float* __restrict__ out,
    int* __restrict__ flags, u64* __restrict__ ring0, u64* __restrict__ ring1)
{
    __shared__ unsigned short hbuf[2][2048];   // 8 KB
    __shared__ unsigned short xbuf[3][2048];   // 12 KB (MODE0 uses 512/slot)
    __shared__ float fcred[16 * HID];          // 8 KB

    const int tid   = threadIdx.x;
    const int wave  = tid >> 6;
    const int lane  = tid & 63;
    const int n16   = lane & 15;
    const int quad  = lane >> 4;

    // bid = ((s>>3)*3 + layer)*8 + (s&7): all 3 stages of slice s on one XCD
    const int xcd    = blockIdx.x & 7;
    const int grp    = blockIdx.x >> 3;
    const int layer  = grp % 3;
    const int sgroup = grp / 3;
    const int slice  = sgroup * 8 + xcd;
    const int bbase  = slice * 16;

    u64* r0 = ring0 + (size_t)slice * (RSLOT * 512);
    u64* r1 = ring1 + (size_t)slice * (RSLOT * 512);
    int* prod0 = flags + (size_t)(0 * 64 + slice) * 64;
    int* prod1 = flags + (size_t)(1 * 64 + slice) * 64;
    int* cons1 = flags + (size_t)(2 * 64 + slice) * 64;
    int* cons2 = flags + (size_t)(3 * 64 + slice) * 64;

    if (layer == 0) {
        run_layer_p<0, false, true, false>(xin, nullptr, r0,
            nullptr, nullptr, cons1, prod0,
            wih0, whh0, bih0, bhh0, hbuf, xbuf, fcred, tid, wave, lane, n16, quad, bbase);
    } else if (layer == 1) {
        run_layer_p<1, true, true, false>(nullptr, r0, r1,
            prod0, cons1, cons2, prod1,
            wih1, whh1, bih1, bhh1, hbuf, xbuf, fcred, tid, wave, lane, n16, quad, bbase);
    } else {
        run_layer_p<1, true, false, true>(nullptr, r1, nullptr,
            prod1, cons2, nullptr, nullptr,
            wih2, whh2, bih2, bhh2, hbuf, xbuf, fcred, tid, wave, lane, n16, quad, bbase);
        __syncthreads();
        if (tid < 16) {
            float s = 0.0f;
#pragma unroll 8
            for (int j = 0; j < HID; ++j) s += fcw[j] * fcred[tid * HID + j];
            out[bbase + tid] = s + fcb[0];
        }
    }
}

extern "C" void kernel_launch(void* const* d_in, const int* in_sizes, int n_in,
                              void* d_out, int out_size, void* d_ws, size_t ws_size,
                              hipStream_t stream) {
    (void)in_sizes; (void)n_in; (void)out_size; (void)ws_size;
    const float* x    = (const float*)d_in[0];
    const float* wih0 = (const float*)d_in[1];
    const float* whh0 = (const float*)d_in[2];
    const float* bih0 = (const float*)d_in[3];
    const float* bhh0 = (const float*)d_in[4];
    const float* wih1 = (const float*)d_in[5];
    const float* whh1 = (const float*)d_in[6];
    const float* bih1 = (const float*)d_in[7];
    const float* bhh1 = (const float*)d_in[8];
    const float* wih2 = (const float*)d_in[9];
    const float* whh2 = (const float*)d_in[10];
    const float* bih2 = (const float*)d_in[11];
    const float* bhh2 = (const float*)d_in[12];
    const float* fcw  = (const float*)d_in[13];
    const float* fcb  = (const float*)d_in[14];
    float* out = (float*)d_out;

    // ws: flags 64 KB (poison-negative = not ready), ring0 4 MB, ring1 4 MB
    int* flags = (int*)d_ws;
    u64* ring0 = (u64*)((char*)d_ws + 65536);
    u64* ring1 = ring0 + (size_t)64 * RSLOT * 512;

    lstm3_pipe_kernel<<<dim3(192), dim3(512), 0, stream>>>(
        x, wih0, whh0, bih0, bhh0, wih1, whh1, bih1, bhh1,
        wih2, whh2, bih2, bhh2, fcw, fcb, out, flags, ring0, ring1);
}